// Round 1
// baseline (309.791 us; speedup 1.0000x reference)
//
#include <hip/hip_runtime.h>

// B-spline basis, DF=16, DEGREE=3, fixed knots:
// KNOTS = [0,0,0] ++ linspace(0, 1+1e-7, 14) ++ [1,1,1]   (20 knots)
// Output shape (32, 131072, 16) float32. Memory-bound: 268 MB out, 17 MB in.

namespace {

struct Tables {
    float knot[20];
    float r1[3][18];   // 1/(knot[p+i]   - knot[i]   + 1e-15), p=1..3
    float r2[3][18];   // 1/(knot[p+1+i] - knot[1+i] + 1e-15)
};

constexpr Tables make_tables() {
    Tables T{};
    const double step = (1.0 + 1e-07) / 13.0;
    for (int i = 0; i < 20; ++i) {
        double v;
        if (i < 3)        v = 0.0;
        else if (i <= 15) v = step * (i - 3);     // linspace pts 0..12
        else if (i == 16) v = 1.0 + 1e-07;        // linspace endpoint exact
        else              v = 1.0;
        T.knot[i] = (float)v;
    }
    for (int p = 1; p <= 3; ++p) {
        for (int i = 0; i < 19 - p; ++i) {
            T.r1[p - 1][i] = 1.0f / (T.knot[p + i]     - T.knot[i]     + 1e-15f);
            T.r2[p - 1][i] = 1.0f / (T.knot[p + 1 + i] - T.knot[1 + i] + 1e-15f);
        }
    }
    return T;
}

} // namespace

__global__ __launch_bounds__(256) void bspline_basis_kernel(
    const float* __restrict__ ts, float* __restrict__ out, int n)
{
    constexpr Tables T = make_tables();

    int gid = blockIdx.x * blockDim.x + threadIdx.x;
    if (gid >= n) return;

    float t = ts[gid];

    // Degree 0: indicator of knot interval (zero-width intervals fold to 0 at
    // compile time since knot[] is constexpr).
    float B[19];
#pragma unroll
    for (int i = 0; i < 19; ++i) {
        float kL = T.knot[i], kR = T.knot[i + 1];
        B[i] = (kR > kL && t >= kL && t < kR) ? 1.0f : 0.0f;
    }

    // Cox-de Boor recursion, denominators pre-reciprocated at compile time.
#pragma unroll
    for (int p = 1; p <= 3; ++p) {
#pragma unroll
        for (int i = 0; i < 19 - p; ++i) {
            float a = (t - T.knot[i]) * T.r1[p - 1][i];
            float b = (T.knot[p + 1 + i] - t) * T.r2[p - 1][i];
            B[i] = a * B[i] + b * B[i + 1];
        }
    }

    // 16 contiguous floats per element -> 4x float4 stores (64 B/thread).
    float4* o = reinterpret_cast<float4*>(out + (size_t)gid * 16);
    o[0] = make_float4(B[0],  B[1],  B[2],  B[3]);
    o[1] = make_float4(B[4],  B[5],  B[6],  B[7]);
    o[2] = make_float4(B[8],  B[9],  B[10], B[11]);
    o[3] = make_float4(B[12], B[13], B[14], B[15]);
}

extern "C" void kernel_launch(void* const* d_in, const int* in_sizes, int n_in,
                              void* d_out, int out_size, void* d_ws, size_t ws_size,
                              hipStream_t stream) {
    const float* ts = (const float*)d_in[0];
    float* out = (float*)d_out;
    int n = in_sizes[0];  // 32 * 131072 = 4194304

    const int block = 256;
    const int grid = (n + block - 1) / block;
    bspline_basis_kernel<<<grid, block, 0, stream>>>(ts, out, n);
}